// Round 4
// baseline (626.144 us; speedup 1.0000x reference)
//
#include <hip/hip_runtime.h>
#include <hip/hip_bf16.h>

#define T_SEQ 256
#define BATCH 1024

typedef __attribute__((ext_vector_type(8))) short  short8;   // 8 bf16 (x32 MFMA frag)
typedef __attribute__((ext_vector_type(4))) short  short4v;  // 4 bf16 (x16 MFMA frag)
typedef __attribute__((ext_vector_type(4))) float  floatx4;  // MFMA C/D frag
typedef unsigned short ushort_t;
typedef unsigned int   uint_t;

template <int P> struct IC { static constexpr int v = P; };

constexpr float NL2E = -1.4426950408889634f;   // -log2(e): sigmoid = rcp(1+exp2(z))
constexpr float L2E2 =  2.8853900817779268f;   // 2*log2(e): tanh = 1-2*rcp(1+exp2(x))

__device__ __forceinline__ float exp2_fast(float x) {
    float r; asm("v_exp_f32 %0, %1" : "=v"(r) : "v"(x)); return r;
}
__device__ __forceinline__ float rcp_fast(float x) {
    float r; asm("v_rcp_f32 %0, %1" : "=v"(r) : "v"(x)); return r;
}
__device__ __forceinline__ ushort_t f2bf(float f) {
    union { float f; uint_t u; } v; v.f = f;
    uint_t r = v.u + 0x7FFFu + ((v.u >> 16) & 1u);   // RNE
    return (ushort_t)(r >> 16);
}
__device__ __forceinline__ uint_t pk_bf16(float a, float b) {
    union { __hip_bfloat162 h; uint_t u; } v;
    v.h = __float22bfloat162_rn(make_float2(a, b));
    return v.u;
}
// Barrier WITHOUT vmcnt drain: LDS ordering only; global loads/stores stay in flight.
__device__ __forceinline__ void sync_lds() {
    asm volatile("s_waitcnt lgkmcnt(0)\n\ts_barrier" ::: "memory");
}

// ============================= MODE ledger (measured) =============================
// MODE 0 = CLASSIC : mfma(A=in, B=w). L1: 167.8-170.8us (R0/R3).
// MODE 1 = SWAP    : mfma(A=w, B=in); lane holds 4 consecutive units of one row.
//                    L2: ~120us (R2/R3). L1: 200us (R0/R2) -> never SWAP L1.
//                    L3 single-wave: ~207us (R3) -> latency-bound, retired for DUAL.
// MODE 2 = REGH    : SWAP + h in regs via 16x16x16 MFMA. L2: 231us (spills, R1).
//                    L3: ~199us (R1/R2). Retired.
// DUAL (R4)        : SWAP + fwd & bwd recurrences in ONE wave -> 2 independent
//                    chains fill each other's latency bubbles. L3 only (VGPR fits).
// R4: accumulator CHAIN SPLIT everywhere: accx (bias+x, off h-critical-path) and
// acch (zero-C h-MFMAs, split per KSh), merged by vector adds. Cuts dependent-MFMA
// depth on the recurrence path from KSx+KSh to 1.
// =================================================================================
__device__ __forceinline__ floatx4 mfma16(short4v a, short4v b, floatx4 c) {
#if __has_builtin(__builtin_amdgcn_mfma_f32_16x16x16bf16_1k)
    return __builtin_amdgcn_mfma_f32_16x16x16bf16_1k(a, b, c, 0, 0, 0);
#else
    floatx4 d;
    asm("v_mfma_f32_16x16x16_bf16 %0, %1, %2, %3" : "=v"(d) : "v"(a), "v"(b), "v"(c));
    return d;
#endif
}

// Fused persistent LSTM layer (one kernel per layer, NO xz materialization).
template <int D, int H, bool IS_FIRST, bool SEQ_OUT, int MODE>
__global__ __launch_bounds__(MODE == 2 ? 64 : 64 * (H / 16), 1) void lstm_fused(
    const void* __restrict__ xin,
    const float* __restrict__ Wf, const float* __restrict__ Uf, const float* __restrict__ bgf,
    const float* __restrict__ Wb, const float* __restrict__ Ub, const float* __restrict__ bgb,
    void* __restrict__ outp)
{
    constexpr bool SW   = (MODE >= 1);           // swapped operand order
    constexpr bool REGH = (MODE == 2);
    constexpr int UG  = REGH ? 1 : H / 16;       // waves per block
    constexpr int NT  = REGH ? H / 16 : 1;       // m-tiles per wave per gate
    constexpr int KSx = D / 32;                  // x k-chunks (16x16x32)
    constexpr int KSh = REGH ? 1 : (H + 31) / 32;// LDS-h k-chunks (1 or 2)
    constexpr int NC  = REGH ? H / 16 : 1;       // register-h k-chunks (16x16x16)
    constexpr int HP  = (H < 32 ? 32 : H) + 8;   // padded h row stride (u16)
    constexpr int G4  = 4 * H;
    constexpr int NTH = 64 * UG;
    static_assert(D % 32 == 0 && T_SEQ % 4 == 0 && KSh <= 2, "shape");

    const int tid  = threadIdx.x;
    const int ug   = tid >> 6;
    const int lane = tid & 63;
    const int lm   = lane & 15;
    const int lq   = lane >> 4;
    const int dir  = blockIdx.y;
    const int b0   = blockIdx.x * 16;

    const float* W  = dir ? Wb  : Wf;
    const float* U  = dir ? Ub  : Uf;
    const float* bg = dir ? bgb : bgf;

    __shared__ __align__(16) ushort_t hbuf[REGH ? 8 : 2 * 16 * HP];

    // ---- one-time weight prepack (pre-scaled). Frags identical for all modes. ----
    short8  aw[4][NT][KSx];   // W^T frags
    short8  hw[4][NT][KSh];   // U^T frags (LDS-h path)
    short4v uw[4][NT][NC];    // U^T x16 frags (REGH path; unused otherwise)
    floatx4 bias4[4][NT];     // persistent bias as MFMA C operand
#pragma unroll
    for (int g = 0; g < 4; g++) {
        const float sc = (g == 2) ? L2E2 : NL2E;
#pragma unroll
        for (int t = 0; t < NT; t++) {
            const int ub = g * H + (REGH ? t * 16 : ug * 16);
            floatx4 b4;
#pragma unroll
            for (int r = 0; r < 4; r++)
                b4[r] = sc * bg[ub + (SW ? lq * 4 + r : lm)];   // classic: bcast over rows
            bias4[g][t] = b4;
            const int nc = ub + lm;
#pragma unroll
            for (int ks = 0; ks < KSx; ks++) {
                short8 f;
#pragma unroll
                for (int e = 0; e < 8; e++)
                    f[e] = (short)f2bf(sc * W[(ks * 32 + lq * 8 + e) * G4 + nc]);
                aw[g][t][ks] = f;
            }
            if constexpr (!REGH) {
#pragma unroll
                for (int ks = 0; ks < KSh; ks++) {
                    short8 f;
#pragma unroll
                    for (int e = 0; e < 8; e++) {
                        const int k = ks * 32 + lq * 8 + e;
                        f[e] = (k < H) ? (short)f2bf(sc * U[k * G4 + nc]) : (short)0;
                    }
                    hw[g][t][ks] = f;
                }
            } else {
#pragma unroll
                for (int c = 0; c < NC; c++) {
                    short4v f;
#pragma unroll
                    for (int e = 0; e < 4; e++)
                        f[e] = (short)f2bf(sc * U[(c * 16 + lq * 4 + e) * G4 + nc]);
                    uw[g][t][c] = f;
                }
            }
        }
    }

    if constexpr (!REGH) {
        for (int idx = tid; idx < 2 * 16 * HP; idx += NTH)
            hbuf[idx] = 0;   // h0 = 0; k-padding stays 0 forever
    }

    const floatx4 zero4 = {0.f, 0.f, 0.f, 0.f};   // persistent zero C for acch
    float   cst[NT][4];      // holds 2log2e * c
    float   hl[NT][4];
    short4v hfrag[NC];       // REGH only
#pragma unroll
    for (int t = 0; t < NT; t++)
#pragma unroll
        for (int r = 0; r < 4; r++) { cst[t][r] = 0.f; hl[t][r] = 0.f; }
    if constexpr (REGH) {
#pragma unroll
        for (int c = 0; c < NC; c++) hfrag[c] = (short4v){0, 0, 0, 0};
    }

    const int t0 = dir ? T_SEQ - 1 : 0;
    // stepping pointers (no per-step 64-bit muls); x loads identical across modes
    const float*    pxf = (const float*)xin + ((size_t)(b0 + lm) * T_SEQ + t0) * D + lq * 8;
    const ushort_t* pxb = (const ushort_t*)xin + ((size_t)t0 * BATCH + b0 + lm) * D + lq * 8;
    const long xstepf = dir ? -(long)D : (long)D;
    const long xstepb = (dir ? -(long)BATCH : (long)BATCH) * D;
    // output pointer, mode-dependent lane->element map
    ushort_t* pout;
    if constexpr (SW)
        pout = (ushort_t*)outp + ((size_t)t0 * BATCH + b0 + lm) * (2 * H) + dir * H +
               (REGH ? 0 : ug * 16) + lq * 4;
    else
        pout = (ushort_t*)outp + ((size_t)t0 * BATCH + b0 + lq * 4) * (2 * H) + dir * H +
               ug * 16 + lm;
    const long ostep = (dir ? -(long)BATCH : (long)BATCH) * (2 * H);

    // x prefetch ring, depth 4
    float4 rawf[4][2 * KSx];   // layer-1 path (fp32 input); DCE'd otherwise
    short8 rawb[4][KSx];       // bf16 path

    auto load_slot = [&](auto sl_) {
        constexpr int SL = decltype(sl_)::v;
        if (IS_FIRST) {
#pragma unroll
            for (int ks = 0; ks < KSx; ks++) {
                rawf[SL][2 * ks + 0] = *(const float4*)(pxf + ks * 32 + 0);
                rawf[SL][2 * ks + 1] = *(const float4*)(pxf + ks * 32 + 4);
            }
            pxf += xstepf;
        } else {
#pragma unroll
            for (int ks = 0; ks < KSx; ks++)
                rawb[SL][ks] = *(const short8*)(pxb + ks * 32);
            pxb += xstepb;
        }
    };

    load_slot(IC<0>{}); load_slot(IC<1>{}); load_slot(IC<2>{}); load_slot(IC<3>{});
    if constexpr (!REGH) __syncthreads();   // hbuf zeros visible

    auto step = [&](auto p_, auto sl_, int s) {
        constexpr int P  = decltype(p_)::v;
        constexpr int SL = decltype(sl_)::v;

        // h frags from LDS (issued first; x-MFMAs overlap the lgkm latency)
        short8 fh[KSh];
        if constexpr (!REGH) {
#pragma unroll
            for (int ks = 0; ks < KSh; ks++)
                fh[ks] = *(const short8*)&hbuf[(P * 16 + lm) * HP + ks * 32 + lq * 8];
        }

        // x frags from the register ring (packed fp32->bf16 conv on layer 1)
        short8 av[KSx];
        if (IS_FIRST) {
#pragma unroll
            for (int ks = 0; ks < KSx; ks++) {
                union { short8 s; uint_t u[4]; } f;
                const float* ra = (const float*)&rawf[SL][2 * ks];
#pragma unroll
                for (int e = 0; e < 4; e++) f.u[e] = pk_bf16(ra[2 * e], ra[2 * e + 1]);
                av[ks] = f.s;
            }
        } else {
#pragma unroll
            for (int ks = 0; ks < KSx; ks++) av[ks] = rawb[SL][ks];
        }

        // ---- x-part: bias-init chain, OFF the h-critical path ----
        floatx4 accx[4][NT];
#pragma unroll
        for (int g = 0; g < 4; g++)
#pragma unroll
            for (int t = 0; t < NT; t++)
                accx[g][t] = SW
                    ? __builtin_amdgcn_mfma_f32_16x16x32_bf16(aw[g][t][0], av[0], bias4[g][t], 0, 0, 0)
                    : __builtin_amdgcn_mfma_f32_16x16x32_bf16(av[0], aw[g][t][0], bias4[g][t], 0, 0, 0);
#pragma unroll
        for (int ks = 1; ks < KSx; ks++)
#pragma unroll
            for (int g = 0; g < 4; g++)
#pragma unroll
                for (int t = 0; t < NT; t++)
                    accx[g][t] = SW
                        ? __builtin_amdgcn_mfma_f32_16x16x32_bf16(aw[g][t][ks], av[ks], accx[g][t], 0, 0, 0)
                        : __builtin_amdgcn_mfma_f32_16x16x32_bf16(av[ks], aw[g][t][ks], accx[g][t], 0, 0, 0);

        if (s + 4 < T_SEQ) load_slot(sl_);   // refill consumed slot (uniform branch)

        // ---- h-part: zero-C, dependent-MFMA depth 1 (KSh accs in parallel) ----
        floatx4 acch[4][NT];
        floatx4 acch2[4][NT];
        if constexpr (!REGH) {
#pragma unroll
            for (int g = 0; g < 4; g++)
#pragma unroll
                for (int t = 0; t < NT; t++)
                    acch[g][t] = SW
                        ? __builtin_amdgcn_mfma_f32_16x16x32_bf16(hw[g][t][0], fh[0], zero4, 0, 0, 0)
                        : __builtin_amdgcn_mfma_f32_16x16x32_bf16(fh[0], hw[g][t][0], zero4, 0, 0, 0);
            if constexpr (KSh == 2) {
#pragma unroll
                for (int g = 0; g < 4; g++)
#pragma unroll
                    for (int t = 0; t < NT; t++)
                        acch2[g][t] = SW
                            ? __builtin_amdgcn_mfma_f32_16x16x32_bf16(hw[g][t][1], fh[1], zero4, 0, 0, 0)
                            : __builtin_amdgcn_mfma_f32_16x16x32_bf16(fh[1], hw[g][t][1], zero4, 0, 0, 0);
            }
        } else {
#pragma unroll
            for (int c = 0; c < NC; c++)
#pragma unroll
                for (int g = 0; g < 4; g++)
#pragma unroll
                    for (int t = 0; t < NT; t++)
                        accx[g][t] = mfma16(uw[g][t][c], hfrag[c], accx[g][t]);
        }

        // gates + c/h update, pure-register (pre-scaled z; cst = 2log2e*c)
#pragma unroll
        for (int t = 0; t < NT; t++) {
            floatx4 zf[4];
#pragma unroll
            for (int g = 0; g < 4; g++) {
                if constexpr (REGH)          zf[g] = accx[g][t];
                else if constexpr (KSh == 2) zf[g] = accx[g][t] + acch[g][t] + acch2[g][t];
                else                         zf[g] = accx[g][t] + acch[g][t];
            }
            float hv[4];
#pragma unroll
            for (int r = 0; r < 4; r++) {
                const float gi = rcp_fast(1.0f + exp2_fast(zf[0][r]));
                const float gf = rcp_fast(1.0f + exp2_fast(zf[1][r]));
                const float gg = 1.0f - 2.0f * rcp_fast(1.0f + exp2_fast(zf[2][r]));
                const float go = rcp_fast(1.0f + exp2_fast(zf[3][r]));
                cst[t][r] = fmaf(gf, cst[t][r], L2E2 * (gi * gg));
                const float tc = 1.0f - 2.0f * rcp_fast(1.0f + exp2_fast(cst[t][r]));
                hv[r] = go * tc;
            }
            if constexpr (SW) {
                const uint_t d0 = pk_bf16(hv[0], hv[1]);   // units +0,+1
                const uint_t d1 = pk_bf16(hv[2], hv[3]);   // units +2,+3
                if constexpr (REGH) {
                    union { uint_t u[2]; short4v s; } pp;
                    pp.u[0] = d0; pp.u[1] = d1;
                    hfrag[t] = pp.s;
                } else {
                    uint2 wv; wv.x = d0; wv.y = d1;
                    *(uint2*)&hbuf[((P ^ 1) * 16 + lm) * HP + ug * 16 + lq * 4] = wv;   // 1x b64
                }
                if (SEQ_OUT) {
                    uint2 ov; ov.x = d0; ov.y = d1;
                    *(uint2*)&pout[t * 16] = ov;            // 1x dwordx2
                } else {
#pragma unroll
                    for (int r = 0; r < 4; r++) hl[t][r] = hv[r];
                }
            } else {
                // classic: lane holds 4 ROWS (lq*4+r) of one unit column (ug*16+lm)
#pragma unroll
                for (int r = 0; r < 4; r++) {
                    const ushort_t hw_ = f2bf(hv[r]);
                    hbuf[((P ^ 1) * 16 + lq * 4 + r) * HP + ug * 16 + lm] = hw_;
                    if (SEQ_OUT) pout[r * 2 * H] = hw_;
                    else         hl[t][r] = hv[r];
                }
            }
        }
        pout += ostep;
        if (UG > 1) sync_lds();   // lgkm-only; single-wave layers need no barrier
    };

    for (int s = 0; s < T_SEQ; s += 4) {
        step(IC<0>{}, IC<0>{}, s);
        step(IC<1>{}, IC<1>{}, s + 1);
        step(IC<0>{}, IC<2>{}, s + 2);
        step(IC<1>{}, IC<3>{}, s + 3);
    }

    if (!SEQ_OUT) {
        float* op = (float*)outp;
        if constexpr (SW) {
#pragma unroll
            for (int t = 0; t < NT; t++) {
                float4 v4 = make_float4(hl[t][0], hl[t][1], hl[t][2], hl[t][3]);
                *(float4*)&op[(size_t)(b0 + lm) * (2 * H) + dir * H +
                              (REGH ? t * 16 : ug * 16) + lq * 4] = v4;
            }
        } else {
#pragma unroll
            for (int r = 0; r < 4; r++)
                op[(size_t)(b0 + lq * 4 + r) * (2 * H) + dir * H + ug * 16 + lm] = hl[0][r];
        }
    }
}

// DUAL-STREAM layer (R4): fwd + bwd recurrences in ONE wave, SWAP layout, no
// barrier. Two independent serial chains interleave in the in-order issue stream,
// hiding each other's MFMA/LDS/act latency. H<=32 (single h k-chunk), bf16 input,
// final-h output only. Ring depth 2 (input is cache-resident).
template <int D, int H>
__global__ __launch_bounds__(64, 1) void lstm_dual(
    const void* __restrict__ xin,
    const float* __restrict__ Wf, const float* __restrict__ Uf, const float* __restrict__ bgf,
    const float* __restrict__ Wb, const float* __restrict__ Ub, const float* __restrict__ bgb,
    float* __restrict__ outp)
{
    constexpr int KSx = D / 32;
    constexpr int HP  = (H < 32 ? 32 : H) + 8;
    constexpr int G4  = 4 * H;
    static_assert(D % 32 == 0 && H <= 32 && T_SEQ % 2 == 0, "dual shape");

    const int lane = threadIdx.x & 63;
    const int lm   = lane & 15;
    const int lq   = lane >> 4;
    const int b0   = blockIdx.x * 16;

    __shared__ __align__(16) ushort_t hbuf[2][2][16][HP];   // [dir][pingpong]

    short8  aw[2][4][KSx];
    short8  hw[2][4];
    floatx4 bias4[2][4];
#pragma unroll
    for (int dd = 0; dd < 2; dd++) {
        const float* W  = dd ? Wb  : Wf;
        const float* U  = dd ? Ub  : Uf;
        const float* bg = dd ? bgb : bgf;
#pragma unroll
        for (int g = 0; g < 4; g++) {
            const float sc = (g == 2) ? L2E2 : NL2E;
            floatx4 b4;
#pragma unroll
            for (int r = 0; r < 4; r++) b4[r] = sc * bg[g * H + lq * 4 + r];
            bias4[dd][g] = b4;
            const int nc = g * H + lm;
#pragma unroll
            for (int ks = 0; ks < KSx; ks++) {
                short8 f;
#pragma unroll
                for (int e = 0; e < 8; e++)
                    f[e] = (short)f2bf(sc * W[(ks * 32 + lq * 8 + e) * G4 + nc]);
                aw[dd][g][ks] = f;
            }
            short8 f;
#pragma unroll
            for (int e = 0; e < 8; e++) {
                const int k = lq * 8 + e;
                f[e] = (k < H) ? (short)f2bf(sc * U[k * G4 + nc]) : (short)0;
            }
            hw[dd][g] = f;
        }
    }
    for (int idx = lane; idx < 2 * 2 * 16 * HP; idx += 64)
        ((ushort_t*)hbuf)[idx] = 0;   // h0 = 0; k-padding stays 0 (within-wave lgkm order)

    float cst[2][4], hl[2][4];
#pragma unroll
    for (int dd = 0; dd < 2; dd++)
#pragma unroll
        for (int r = 0; r < 4; r++) { cst[dd][r] = 0.f; hl[dd][r] = 0.f; }

    const ushort_t* px0 = (const ushort_t*)xin + ((size_t)b0 + lm) * D + lq * 8;
    const ushort_t* px1 = (const ushort_t*)xin +
        ((size_t)(T_SEQ - 1) * BATCH + b0 + lm) * D + lq * 8;
    const long xst = (long)BATCH * D;

    short8 ring[2][2][KSx];   // [dir][slot]
    auto load2 = [&](auto sl_) {
        constexpr int SL = decltype(sl_)::v;
#pragma unroll
        for (int ks = 0; ks < KSx; ks++) ring[0][SL][ks] = *(const short8*)(px0 + ks * 32);
        px0 += xst;
#pragma unroll
        for (int ks = 0; ks < KSx; ks++) ring[1][SL][ks] = *(const short8*)(px1 + ks * 32);
        px1 -= xst;
    };
    load2(IC<0>{}); load2(IC<1>{});

    auto stepd = [&](auto p_, int s) {
        constexpr int P = decltype(p_)::v;   // pingpong == ring slot
        short8 fh0 = *(const short8*)&hbuf[0][P][lm][lq * 8];
        short8 fh1 = *(const short8*)&hbuf[1][P][lm][lq * 8];

        floatx4 acc[2][4];
#pragma unroll
        for (int dd = 0; dd < 2; dd++)
#pragma unroll
            for (int g = 0; g < 4; g++)
                acc[dd][g] = __builtin_amdgcn_mfma_f32_16x16x32_bf16(
                    aw[dd][g][0], ring[dd][P][0], bias4[dd][g], 0, 0, 0);
#pragma unroll
        for (int ks = 1; ks < KSx; ks++)
#pragma unroll
            for (int dd = 0; dd < 2; dd++)
#pragma unroll
                for (int g = 0; g < 4; g++)
                    acc[dd][g] = __builtin_amdgcn_mfma_f32_16x16x32_bf16(
                        aw[dd][g][ks], ring[dd][P][ks], acc[dd][g], 0, 0, 0);

        if (s + 2 < T_SEQ) load2(p_);   // refill consumed slot

#pragma unroll
        for (int g = 0; g < 4; g++)
            acc[0][g] = __builtin_amdgcn_mfma_f32_16x16x32_bf16(hw[0][g], fh0, acc[0][g], 0, 0, 0);
#pragma unroll
        for (int g = 0; g < 4; g++)
            acc[1][g] = __builtin_amdgcn_mfma_f32_16x16x32_bf16(hw[1][g], fh1, acc[1][g], 0, 0, 0);

#pragma unroll
        for (int dd = 0; dd < 2; dd++) {
            float hv[4];
#pragma unroll
            for (int r = 0; r < 4; r++) {
                const float gi = rcp_fast(1.0f + exp2_fast(acc[dd][0][r]));
                const float gf = rcp_fast(1.0f + exp2_fast(acc[dd][1][r]));
                const float gg = 1.0f - 2.0f * rcp_fast(1.0f + exp2_fast(acc[dd][2][r]));
                const float go = rcp_fast(1.0f + exp2_fast(acc[dd][3][r]));
                cst[dd][r] = fmaf(gf, cst[dd][r], L2E2 * (gi * gg));
                const float tc = 1.0f - 2.0f * rcp_fast(1.0f + exp2_fast(cst[dd][r]));
                hv[r] = go * tc;
                hl[dd][r] = hv[r];
            }
            uint2 wv; wv.x = pk_bf16(hv[0], hv[1]); wv.y = pk_bf16(hv[2], hv[3]);
            *(uint2*)&hbuf[dd][P ^ 1][lm][lq * 4] = wv;
        }
    };

    for (int s = 0; s < T_SEQ; s += 2) {
        stepd(IC<0>{}, s);
        stepd(IC<1>{}, s + 1);
    }

#pragma unroll
    for (int dd = 0; dd < 2; dd++) {
        float4 v4 = make_float4(hl[dd][0], hl[dd][1], hl[dd][2], hl[dd][3]);
        *(float4*)&outp[(size_t)(b0 + lm) * (2 * H) + dd * H + lq * 4] = v4;
    }
}

// Dense head: relu6(x@Wd1+bd1) @ Wd2 + bd2 -> softmax(2). One row per thread.
__global__ __launch_bounds__(256) void dense_head(
    const float* __restrict__ h3, const float* __restrict__ Wd1, const float* __restrict__ bd1,
    const float* __restrict__ Wd2, const float* __restrict__ bd2, float* __restrict__ out)
{
    const int b = blockIdx.x * blockDim.x + threadIdx.x;
    if (b >= BATCH) return;
    float x[32];
#pragma unroll
    for (int k = 0; k < 32; k++) x[k] = h3[b * 32 + k];
    float y[16];
#pragma unroll
    for (int jj = 0; jj < 16; jj++) {
        float a = bd1[jj];
#pragma unroll
        for (int k = 0; k < 32; k++) a = fmaf(x[k], Wd1[k * 16 + jj], a);
        y[jj] = fminf(fmaxf(a, 0.0f), 6.0f);
    }
    float l0 = bd2[0], l1 = bd2[1];
#pragma unroll
    for (int k = 0; k < 16; k++) {
        l0 = fmaf(y[k], Wd2[k * 2 + 0], l0);
        l1 = fmaf(y[k], Wd2[k * 2 + 1], l1);
    }
    const float m = fmaxf(l0, l1);
    const float e0 = __expf(l0 - m), e1 = __expf(l1 - m);
    const float inv = 1.0f / (e0 + e1);
    out[b * 2 + 0] = e0 * inv;
    out[b * 2 + 1] = e1 * inv;
}

extern "C" void kernel_launch(void* const* d_in, const int* in_sizes, int n_in,
                              void* d_out, int out_size, void* d_ws, size_t ws_size,
                              hipStream_t stream)
{
    const float* x   = (const float*)d_in[0];
    const float* W1f = (const float*)d_in[1];
    const float* U1f = (const float*)d_in[2];
    const float* b1f = (const float*)d_in[3];
    const float* W1b = (const float*)d_in[4];
    const float* U1b = (const float*)d_in[5];
    const float* b1b = (const float*)d_in[6];
    const float* W2f = (const float*)d_in[7];
    const float* U2f = (const float*)d_in[8];
    const float* b2f = (const float*)d_in[9];
    const float* W2b = (const float*)d_in[10];
    const float* U2b = (const float*)d_in[11];
    const float* b2b = (const float*)d_in[12];
    const float* W3f = (const float*)d_in[13];
    const float* U3f = (const float*)d_in[14];
    const float* b3f = (const float*)d_in[15];
    const float* W3b = (const float*)d_in[16];
    const float* U3b = (const float*)d_in[17];
    const float* b3b = (const float*)d_in[18];
    const float* Wd1 = (const float*)d_in[19];
    const float* bd1 = (const float*)d_in[20];
    const float* Wd2 = (const float*)d_in[21];
    const float* bd2 = (const float*)d_in[22];

    // workspace: 96 MB + 128 KB footprint
    char* ws = (char*)d_ws;
    void*  l1out = (void*)ws;                                  // [T][B][128] bf16 = 64 MB
    void*  l2out = (void*)(ws + (size_t)64 * 1024 * 1024);     // [T][B][64]  bf16 = 32 MB
    float* h3    = (float*)(ws + (size_t)96 * 1024 * 1024);    // [B][32] fp32 = 128 KB
    float* out   = (float*)d_out;

    dim3 grid(BATCH / 16, 2);

    lstm_fused<64, 64, true, true, 0>      // CLASSIC, 4 waves + chain-split
        <<<grid, 256, 0, stream>>>(x, W1f, U1f, b1f, W1b, U1b, b1b, l1out);
    lstm_fused<128, 32, false, true, 1>    // SWAP-LDS, 2 waves + chain-split
        <<<grid, 128, 0, stream>>>(l1out, W2f, U2f, b2f, W2b, U2b, b2b, l2out);
    lstm_dual<64, 16>                      // DUAL: fwd+bwd in one wave, 64 blocks
        <<<dim3(BATCH / 16), 64, 0, stream>>>(l2out, W3f, U3f, b3f, W3b, U3b, b3b, h3);
    dense_head<<<dim3(BATCH / 256), 256, 0, stream>>>(h3, Wd1, bd1, Wd2, bd2, out);
}

// Round 5
// 518.175 us; speedup vs baseline: 1.2084x; 1.2084x over previous
//
#include <hip/hip_runtime.h>
#include <hip/hip_bf16.h>
#include <hip/hip_fp16.h>

#define T_SEQ 256
#define BATCH 1024

typedef __attribute__((ext_vector_type(8))) short  short8;   // 8 bf16 (x32 MFMA frag)
typedef __attribute__((ext_vector_type(4))) short  short4v;  // 4 bf16 (x16 MFMA frag)
typedef __attribute__((ext_vector_type(4))) float  floatx4;  // MFMA C/D frag
typedef unsigned short ushort_t;
typedef unsigned int   uint_t;

template <int P> struct IC { static constexpr int v = P; };

constexpr float NL2E = -1.4426950408889634f;   // -log2(e): sigmoid = rcp(1+exp2(z))
constexpr float L2E2 =  2.8853900817779268f;   // 2*log2(e): tanh = 1-2*rcp(1+exp2(x))

__device__ __forceinline__ float exp2_fast(float x) {
    float r; asm("v_exp_f32 %0, %1" : "=v"(r) : "v"(x)); return r;
}
__device__ __forceinline__ float rcp_fast(float x) {
    float r; asm("v_rcp_f32 %0, %1" : "=v"(r) : "v"(x)); return r;
}
__device__ __forceinline__ ushort_t f2bf(float f) {
    union { float f; uint_t u; } v; v.f = f;
    uint_t r = v.u + 0x7FFFu + ((v.u >> 16) & 1u);   // RNE
    return (ushort_t)(r >> 16);
}
__device__ __forceinline__ uint_t pk_bf16(float a, float b) {
    union { __hip_bfloat162 h; uint_t u; } v;
    v.h = __float22bfloat162_rn(make_float2(a, b));
    return v.u;
}
__device__ __forceinline__ uint_t pk_f16(float a, float b) {
    const uint_t lo = (uint_t)__half_as_ushort(__float2half_rn(a));
    const uint_t hi = (uint_t)__half_as_ushort(__float2half_rn(b));
    return lo | (hi << 16);
}
__device__ __forceinline__ float h2f(uint_t u) {
    return __half2float(__ushort_as_half((ushort_t)u));
}
// Barrier WITHOUT vmcnt drain: LDS ordering only; global loads/stores stay in flight.
__device__ __forceinline__ void sync_lds() {
    asm volatile("s_waitcnt lgkmcnt(0)\n\ts_barrier" ::: "memory");
}

// ============================= Ledger (measured) ==================================
// L1: CLASSIC 4-wave 167.8-170.8us (R0/R3). SWAP: 200us (R0/R2) -> never.
// L2: SWAP-LDS 2-wave ~120us (R2/R3).  REGH: 231us spills (R1).
// L3: swap-1wave 207 (R3) / REGH 199 (R1/R2) / dual 212 (R4).
// R4 lessons: (a) chain-split acc REGRESSED L1+L2 by +115us -> reverted here.
//             (b) dual: +100% work per wave for +3% time -> step is LATENCY-bound
//                 with >=50% bubbles; only removing work FROM THE CHAIN helps.
// R5: L3 = xz hoisted out of the recurrence (xz_gemm, parallel, memory-bound)
//     + lstm_rec: per step just {prefetched xz load -> 4x mfma16 -> act -> pk}.
//     xz3 stored fp16, pre-scaled, bias-folded, in SWAP C'-layout [T*B][dir][g][16];
//     it ALIASES l1out (consumed by then) -> workspace stays 96MB+128KB.
// =================================================================================
__device__ __forceinline__ floatx4 mfma16(short4v a, short4v b, floatx4 c) {
#if __has_builtin(__builtin_amdgcn_mfma_f32_16x16x16bf16_1k)
    return __builtin_amdgcn_mfma_f32_16x16x16bf16_1k(a, b, c, 0, 0, 0);
#else
    floatx4 d;
    asm("v_mfma_f32_16x16x16_bf16 %0, %1, %2, %3" : "=v"(d) : "v"(a), "v"(b), "v"(c));
    return d;
#endif
}

// Fused persistent LSTM layer — EXACT R3 form (measured L1 170.8 / L2 ~120).
template <int D, int H, bool IS_FIRST, bool SEQ_OUT, int MODE>
__global__ __launch_bounds__(MODE == 2 ? 64 : 64 * (H / 16), 1) void lstm_fused(
    const void* __restrict__ xin,
    const float* __restrict__ Wf, const float* __restrict__ Uf, const float* __restrict__ bgf,
    const float* __restrict__ Wb, const float* __restrict__ Ub, const float* __restrict__ bgb,
    void* __restrict__ outp)
{
    constexpr bool SW   = (MODE >= 1);           // swapped operand order
    constexpr bool REGH = (MODE == 2);
    constexpr int UG  = REGH ? 1 : H / 16;       // waves per block
    constexpr int NT  = REGH ? H / 16 : 1;       // m-tiles per wave per gate
    constexpr int KSx = D / 32;                  // x k-chunks (16x16x32)
    constexpr int KSh = REGH ? 1 : (H + 31) / 32;// LDS-h k-chunks
    constexpr int NC  = REGH ? H / 16 : 1;       // register-h k-chunks (16x16x16)
    constexpr int HP  = (H < 32 ? 32 : H) + 8;   // padded h row stride (u16)
    constexpr int G4  = 4 * H;
    constexpr int NTH = 64 * UG;
    static_assert(D % 32 == 0 && T_SEQ % 4 == 0, "shape");

    const int tid  = threadIdx.x;
    const int ug   = tid >> 6;
    const int lane = tid & 63;
    const int lm   = lane & 15;
    const int lq   = lane >> 4;
    const int dir  = blockIdx.y;
    const int b0   = blockIdx.x * 16;

    const float* W  = dir ? Wb  : Wf;
    const float* U  = dir ? Ub  : Uf;
    const float* bg = dir ? bgb : bgf;

    __shared__ __align__(16) ushort_t hbuf[REGH ? 8 : 2 * 16 * HP];

    // ---- one-time weight prepack (pre-scaled). Frags identical for all modes. ----
    short8  aw[4][NT][KSx];   // W^T frags
    short8  hw[4][NT][KSh];   // U^T frags (LDS-h path)
    short4v uw[4][NT][NC];    // U^T x16 frags (REGH path; unused otherwise)
    floatx4 bias4[4][NT];     // persistent bias as MFMA C operand
#pragma unroll
    for (int g = 0; g < 4; g++) {
        const float sc = (g == 2) ? L2E2 : NL2E;
#pragma unroll
        for (int t = 0; t < NT; t++) {
            const int ub = g * H + (REGH ? t * 16 : ug * 16);
            floatx4 b4;
#pragma unroll
            for (int r = 0; r < 4; r++)
                b4[r] = sc * bg[ub + (SW ? lq * 4 + r : lm)];   // classic: bcast over rows
            bias4[g][t] = b4;
            const int nc = ub + lm;
#pragma unroll
            for (int ks = 0; ks < KSx; ks++) {
                short8 f;
#pragma unroll
                for (int e = 0; e < 8; e++)
                    f[e] = (short)f2bf(sc * W[(ks * 32 + lq * 8 + e) * G4 + nc]);
                aw[g][t][ks] = f;
            }
            if constexpr (!REGH) {
#pragma unroll
                for (int ks = 0; ks < KSh; ks++) {
                    short8 f;
#pragma unroll
                    for (int e = 0; e < 8; e++) {
                        const int k = ks * 32 + lq * 8 + e;
                        f[e] = (k < H) ? (short)f2bf(sc * U[k * G4 + nc]) : (short)0;
                    }
                    hw[g][t][ks] = f;
                }
            } else {
#pragma unroll
                for (int c = 0; c < NC; c++) {
                    short4v f;
#pragma unroll
                    for (int e = 0; e < 4; e++)
                        f[e] = (short)f2bf(sc * U[(c * 16 + lq * 4 + e) * G4 + nc]);
                    uw[g][t][c] = f;
                }
            }
        }
    }

    if constexpr (!REGH) {
        for (int idx = tid; idx < 2 * 16 * HP; idx += NTH)
            hbuf[idx] = 0;   // h0 = 0; k-padding stays 0 forever
    }

    float   cst[NT][4];      // holds 2log2e * c
    float   hl[NT][4];
    short4v hfrag[NC];       // REGH only
#pragma unroll
    for (int t = 0; t < NT; t++)
#pragma unroll
        for (int r = 0; r < 4; r++) { cst[t][r] = 0.f; hl[t][r] = 0.f; }
    if constexpr (REGH) {
#pragma unroll
        for (int c = 0; c < NC; c++) hfrag[c] = (short4v){0, 0, 0, 0};
    }

    const int t0 = dir ? T_SEQ - 1 : 0;
    // stepping pointers (no per-step 64-bit muls); x loads identical across modes
    const float*    pxf = (const float*)xin + ((size_t)(b0 + lm) * T_SEQ + t0) * D + lq * 8;
    const ushort_t* pxb = (const ushort_t*)xin + ((size_t)t0 * BATCH + b0 + lm) * D + lq * 8;
    const long xstepf = dir ? -(long)D : (long)D;
    const long xstepb = (dir ? -(long)BATCH : (long)BATCH) * D;
    // output pointer, mode-dependent lane->element map
    ushort_t* pout;
    if constexpr (SW)
        pout = (ushort_t*)outp + ((size_t)t0 * BATCH + b0 + lm) * (2 * H) + dir * H +
               (REGH ? 0 : ug * 16) + lq * 4;
    else
        pout = (ushort_t*)outp + ((size_t)t0 * BATCH + b0 + lq * 4) * (2 * H) + dir * H +
               ug * 16 + lm;
    const long ostep = (dir ? -(long)BATCH : (long)BATCH) * (2 * H);

    // x prefetch ring, depth 4
    float4 rawf[4][2 * KSx];   // layer-1 path (fp32 input); DCE'd otherwise
    short8 rawb[4][KSx];       // bf16 path

    auto load_slot = [&](auto sl_) {
        constexpr int SL = decltype(sl_)::v;
        if (IS_FIRST) {
#pragma unroll
            for (int ks = 0; ks < KSx; ks++) {
                rawf[SL][2 * ks + 0] = *(const float4*)(pxf + ks * 32 + 0);
                rawf[SL][2 * ks + 1] = *(const float4*)(pxf + ks * 32 + 4);
            }
            pxf += xstepf;
        } else {
#pragma unroll
            for (int ks = 0; ks < KSx; ks++)
                rawb[SL][ks] = *(const short8*)(pxb + ks * 32);
            pxb += xstepb;
        }
    };

    load_slot(IC<0>{}); load_slot(IC<1>{}); load_slot(IC<2>{}); load_slot(IC<3>{});
    if constexpr (!REGH) __syncthreads();   // hbuf zeros visible

    auto step = [&](auto p_, auto sl_, int s) {
        constexpr int P  = decltype(p_)::v;
        constexpr int SL = decltype(sl_)::v;

        // h frags from LDS (issued first; x-MFMAs overlap the lgkm latency)
        short8 fh[KSh];
        if constexpr (!REGH) {
#pragma unroll
            for (int ks = 0; ks < KSh; ks++)
                fh[ks] = *(const short8*)&hbuf[(P * 16 + lm) * HP + ks * 32 + lq * 8];
        }

        // x frags from the register ring (packed fp32->bf16 conv on layer 1)
        short8 av[KSx];
        if (IS_FIRST) {
#pragma unroll
            for (int ks = 0; ks < KSx; ks++) {
                union { short8 s; uint_t u[4]; } f;
                const float* ra = (const float*)&rawf[SL][2 * ks];
#pragma unroll
                for (int e = 0; e < 4; e++) f.u[e] = pk_bf16(ra[2 * e], ra[2 * e + 1]);
                av[ks] = f.s;
            }
        } else {
#pragma unroll
            for (int ks = 0; ks < KSx; ks++) av[ks] = rawb[SL][ks];
        }

        floatx4 acc[4][NT];
        // first x-MFMA carries the (persistent) bias as C — no per-step init movs
#pragma unroll
        for (int g = 0; g < 4; g++)
#pragma unroll
            for (int t = 0; t < NT; t++)
                acc[g][t] = SW
                    ? __builtin_amdgcn_mfma_f32_16x16x32_bf16(aw[g][t][0], av[0], bias4[g][t], 0, 0, 0)
                    : __builtin_amdgcn_mfma_f32_16x16x32_bf16(av[0], aw[g][t][0], bias4[g][t], 0, 0, 0);
#pragma unroll
        for (int ks = 1; ks < KSx; ks++)
#pragma unroll
            for (int g = 0; g < 4; g++)
#pragma unroll
                for (int t = 0; t < NT; t++)
                    acc[g][t] = SW
                        ? __builtin_amdgcn_mfma_f32_16x16x32_bf16(aw[g][t][ks], av[ks], acc[g][t], 0, 0, 0)
                        : __builtin_amdgcn_mfma_f32_16x16x32_bf16(av[ks], aw[g][t][ks], acc[g][t], 0, 0, 0);

        if (s + 4 < T_SEQ) load_slot(sl_);   // refill consumed slot (uniform branch)

        // recurrent part last (shortest possible h -> MFMA distance)
        if constexpr (!REGH) {
#pragma unroll
            for (int ks = 0; ks < KSh; ks++)
#pragma unroll
                for (int g = 0; g < 4; g++)
                    acc[g][0] = SW
                        ? __builtin_amdgcn_mfma_f32_16x16x32_bf16(hw[g][0][ks], fh[ks], acc[g][0], 0, 0, 0)
                        : __builtin_amdgcn_mfma_f32_16x16x32_bf16(fh[ks], hw[g][0][ks], acc[g][0], 0, 0, 0);
        } else {
#pragma unroll
            for (int c = 0; c < NC; c++)
#pragma unroll
                for (int g = 0; g < 4; g++)
#pragma unroll
                    for (int t = 0; t < NT; t++)
                        acc[g][t] = mfma16(uw[g][t][c], hfrag[c], acc[g][t]);
        }

        // gates + c/h update, pure-register (pre-scaled z; cst = 2log2e*c)
#pragma unroll
        for (int t = 0; t < NT; t++) {
            float hv[4];
#pragma unroll
            for (int r = 0; r < 4; r++) {
                const float gi = rcp_fast(1.0f + exp2_fast(acc[0][t][r]));
                const float gf = rcp_fast(1.0f + exp2_fast(acc[1][t][r]));
                const float gg = 1.0f - 2.0f * rcp_fast(1.0f + exp2_fast(acc[2][t][r]));
                const float go = rcp_fast(1.0f + exp2_fast(acc[3][t][r]));
                cst[t][r] = fmaf(gf, cst[t][r], L2E2 * (gi * gg));
                const float tc = 1.0f - 2.0f * rcp_fast(1.0f + exp2_fast(cst[t][r]));
                hv[r] = go * tc;
            }
            if constexpr (SW) {
                const uint_t d0 = pk_bf16(hv[0], hv[1]);   // units +0,+1
                const uint_t d1 = pk_bf16(hv[2], hv[3]);   // units +2,+3
                if constexpr (REGH) {
                    union { uint_t u[2]; short4v s; } pp;
                    pp.u[0] = d0; pp.u[1] = d1;
                    hfrag[t] = pp.s;
                } else {
                    uint2 wv; wv.x = d0; wv.y = d1;
                    *(uint2*)&hbuf[((P ^ 1) * 16 + lm) * HP + ug * 16 + lq * 4] = wv;   // 1x b64
                }
                if (SEQ_OUT) {
                    uint2 ov; ov.x = d0; ov.y = d1;
                    *(uint2*)&pout[t * 16] = ov;            // 1x dwordx2
                } else {
#pragma unroll
                    for (int r = 0; r < 4; r++) hl[t][r] = hv[r];
                }
            } else {
                // classic: lane holds 4 ROWS (lq*4+r) of one unit column (ug*16+lm)
#pragma unroll
                for (int r = 0; r < 4; r++) {
                    const ushort_t hw_ = f2bf(hv[r]);
                    hbuf[((P ^ 1) * 16 + lq * 4 + r) * HP + ug * 16 + lm] = hw_;
                    if (SEQ_OUT) pout[r * 2 * H] = hw_;
                    else         hl[t][r] = hv[r];
                }
            }
        }
        pout += ostep;
        if (UG > 1) sync_lds();   // lgkm-only; single-wave layers need no barrier
    };

    for (int s = 0; s < T_SEQ; s += 4) {
        step(IC<0>{}, IC<0>{}, s);
        step(IC<1>{}, IC<1>{}, s + 1);
        step(IC<0>{}, IC<2>{}, s + 2);
        step(IC<1>{}, IC<3>{}, s + 3);
    }

    if (!SEQ_OUT) {
        float* op = (float*)outp;
        if constexpr (SW) {
#pragma unroll
            for (int t = 0; t < NT; t++) {
                float4 v4 = make_float4(hl[t][0], hl[t][1], hl[t][2], hl[t][3]);
                *(float4*)&op[(size_t)(b0 + lm) * (2 * H) + dir * H +
                              (REGH ? t * 16 : ug * 16) + lq * 4] = v4;
            }
        } else {
#pragma unroll
            for (int r = 0; r < 4; r++)
                op[(size_t)(b0 + lq * 4 + r) * (2 * H) + dir * H + ug * 16 + lm] = hl[0][r];
        }
    }
}

// xz hoist for L3 (R5): XZ3[t*B+b][dir][gate][16] fp16 = sc_g*(l2out[t,b,:]@W3 + b3).
// Fully parallel memory-bound GEMM (~96MB traffic). Output layout = SWAP C' map so
// the recurrence lane (row=lm, units lq*4+r) reads one uint2 per gate.
__global__ __launch_bounds__(256) void xz_gemm(
    const ushort_t* __restrict__ xin,   // [T*B][64] bf16 (l2out)
    const float* __restrict__ Wf, const float* __restrict__ bgf,
    const float* __restrict__ Wb, const float* __restrict__ bgb,
    ushort_t* __restrict__ xz)          // [T*B][2][4][16] fp16
{
    constexpr int DIN = 64, HH = 16, G4 = 64, KS = 2;
    const int tid = threadIdx.x, ug = tid >> 6, lane = tid & 63;
    const int lm = lane & 15, lq = lane >> 4;

    short8  aw[2][4][KS];
    floatx4 bias4[2][4];
#pragma unroll
    for (int dd = 0; dd < 2; dd++) {
        const float* W  = dd ? Wb  : Wf;
        const float* bg = dd ? bgb : bgf;
#pragma unroll
        for (int g = 0; g < 4; g++) {
            const float sc = (g == 2) ? L2E2 : NL2E;
            floatx4 b4;
#pragma unroll
            for (int r = 0; r < 4; r++) b4[r] = sc * bg[g * HH + lq * 4 + r];
            bias4[dd][g] = b4;
#pragma unroll
            for (int ks = 0; ks < KS; ks++) {
                short8 f;
#pragma unroll
                for (int e = 0; e < 8; e++)
                    f[e] = (short)f2bf(sc * W[(ks * 32 + lq * 8 + e) * G4 + g * HH + lm]);
                aw[dd][g][ks] = f;
            }
        }
    }

    const int NW    = gridDim.x * 4;            // total waves
    const int w0    = blockIdx.x * 4 + ug;
    const int NTILE = (T_SEQ * BATCH) / 16;     // 16384 row-tiles
    for (int tile = w0; tile < NTILE; tile += NW) {
        const size_t row = (size_t)tile * 16 + lm;
        short8 xv[KS];
#pragma unroll
        for (int ks = 0; ks < KS; ks++)
            xv[ks] = *(const short8*)&xin[row * DIN + ks * 32 + lq * 8];
#pragma unroll
        for (int dd = 0; dd < 2; dd++)
#pragma unroll
            for (int g = 0; g < 4; g++) {
                floatx4 a = __builtin_amdgcn_mfma_f32_16x16x32_bf16(aw[dd][g][0], xv[0], bias4[dd][g], 0, 0, 0);
                a = __builtin_amdgcn_mfma_f32_16x16x32_bf16(aw[dd][g][1], xv[1], a, 0, 0, 0);
                uint2 st;
                st.x = pk_f16(a[0], a[1]);
                st.y = pk_f16(a[2], a[3]);
                *(uint2*)&xz[row * 128 + dd * 64 + g * HH + lq * 4] = st;
            }
    }
}

// L3 recurrence with xz hoisted (R5): per step just {prefetched xz -> 4 independent
// mfma16 (C = xz) -> act -> cvt_pk -> hfrag}. Register-resident h (verified REGH
// frag identity: pk output IS the 16x16x16 B-frag). No LDS, no barrier, ~60 VGPR.
template <int H>
__global__ __launch_bounds__(64, 1) void lstm_rec(
    const ushort_t* __restrict__ xz,   // [T*B][2][4][H] fp16, pre-scaled, bias folded
    const float* __restrict__ Uf, const float* __restrict__ Ub,
    float* __restrict__ outp)          // [B][2*H] fp32 (final h)
{
    static_assert(H == 16 && T_SEQ % 4 == 0, "rec shape");
    const int lane = threadIdx.x & 63;
    const int lm   = lane & 15;
    const int lq   = lane >> 4;
    const int dir  = blockIdx.y;
    const int b0   = blockIdx.x * 16;
    const float* U = dir ? Ub : Uf;

    short4v uw[4];
#pragma unroll
    for (int g = 0; g < 4; g++) {
        const float sc = (g == 2) ? L2E2 : NL2E;
        short4v f;
#pragma unroll
        for (int e = 0; e < 4; e++)
            f[e] = (short)f2bf(sc * U[(lq * 4 + e) * (4 * H) + g * H + lm]);
        uw[g] = f;
    }

    short4v hfrag = (short4v){0, 0, 0, 0};
    float cst[4] = {0.f, 0.f, 0.f, 0.f};
    float hl[4]  = {0.f, 0.f, 0.f, 0.f};

    const int t0 = dir ? T_SEQ - 1 : 0;
    const ushort_t* pz = xz + ((size_t)t0 * BATCH + b0 + lm) * 128 + dir * 64 + lq * 4;
    const long zstep = (dir ? -(long)BATCH : (long)BATCH) * 128;

    uint2 rz[4][4];   // prefetch ring [slot][gate], depth 4
    auto load_slot = [&](auto sl_) {
        constexpr int SL = decltype(sl_)::v;
#pragma unroll
        for (int g = 0; g < 4; g++)
            rz[SL][g] = *(const uint2*)(pz + g * 16);
        pz += zstep;
    };
    load_slot(IC<0>{}); load_slot(IC<1>{}); load_slot(IC<2>{}); load_slot(IC<3>{});

    auto step = [&](auto sl_, int s) {
        constexpr int SL = decltype(sl_)::v;
        floatx4 acc[4];
#pragma unroll
        for (int g = 0; g < 4; g++) {
            floatx4 zc;
            zc[0] = h2f(rz[SL][g].x & 0xffffu);
            zc[1] = h2f(rz[SL][g].x >> 16);
            zc[2] = h2f(rz[SL][g].y & 0xffffu);
            zc[3] = h2f(rz[SL][g].y >> 16);
            acc[g] = mfma16(uw[g], hfrag, zc);   // 4 independent, depth-1 chain
        }
        if (s + 4 < T_SEQ) load_slot(sl_);       // refill consumed slot

        float hv[4];
#pragma unroll
        for (int r = 0; r < 4; r++) {
            const float gi = rcp_fast(1.0f + exp2_fast(acc[0][r]));
            const float gf = rcp_fast(1.0f + exp2_fast(acc[1][r]));
            const float gg = 1.0f - 2.0f * rcp_fast(1.0f + exp2_fast(acc[2][r]));
            const float go = rcp_fast(1.0f + exp2_fast(acc[3][r]));
            cst[r] = fmaf(gf, cst[r], L2E2 * (gi * gg));
            const float tc = 1.0f - 2.0f * rcp_fast(1.0f + exp2_fast(cst[r]));
            hv[r] = go * tc;
            hl[r] = hv[r];
        }
        union { uint_t u[2]; short4v s4; } pp;
        pp.u[0] = pk_bf16(hv[0], hv[1]);
        pp.u[1] = pk_bf16(hv[2], hv[3]);
        hfrag = pp.s4;                            // next step's h B-frag, in-register
    };

    for (int s = 0; s < T_SEQ; s += 4) {
        step(IC<0>{}, s);
        step(IC<1>{}, s + 1);
        step(IC<2>{}, s + 2);
        step(IC<3>{}, s + 3);
    }

    float4 v4 = make_float4(hl[0], hl[1], hl[2], hl[3]);
    *(float4*)&outp[(size_t)(b0 + lm) * (2 * H) + dir * H + lq * 4] = v4;
}

// Dense head: relu6(x@Wd1+bd1) @ Wd2 + bd2 -> softmax(2). One row per thread.
__global__ __launch_bounds__(256) void dense_head(
    const float* __restrict__ h3, const float* __restrict__ Wd1, const float* __restrict__ bd1,
    const float* __restrict__ Wd2, const float* __restrict__ bd2, float* __restrict__ out)
{
    const int b = blockIdx.x * blockDim.x + threadIdx.x;
    if (b >= BATCH) return;
    float x[32];
#pragma unroll
    for (int k = 0; k < 32; k++) x[k] = h3[b * 32 + k];
    float y[16];
#pragma unroll
    for (int jj = 0; jj < 16; jj++) {
        float a = bd1[jj];
#pragma unroll
        for (int k = 0; k < 32; k++) a = fmaf(x[k], Wd1[k * 16 + jj], a);
        y[jj] = fminf(fmaxf(a, 0.0f), 6.0f);
    }
    float l0 = bd2[0], l1 = bd2[1];
#pragma unroll
    for (int k = 0; k < 16; k++) {
        l0 = fmaf(y[k], Wd2[k * 2 + 0], l0);
        l1 = fmaf(y[k], Wd2[k * 2 + 1], l1);
    }
    const float m = fmaxf(l0, l1);
    const float e0 = __expf(l0 - m), e1 = __expf(l1 - m);
    const float inv = 1.0f / (e0 + e1);
    out[b * 2 + 0] = e0 * inv;
    out[b * 2 + 1] = e1 * inv;
}

extern "C" void kernel_launch(void* const* d_in, const int* in_sizes, int n_in,
                              void* d_out, int out_size, void* d_ws, size_t ws_size,
                              hipStream_t stream)
{
    const float* x   = (const float*)d_in[0];
    const float* W1f = (const float*)d_in[1];
    const float* U1f = (const float*)d_in[2];
    const float* b1f = (const float*)d_in[3];
    const float* W1b = (const float*)d_in[4];
    const float* U1b = (const float*)d_in[5];
    const float* b1b = (const float*)d_in[6];
    const float* W2f = (const float*)d_in[7];
    const float* U2f = (const float*)d_in[8];
    const float* b2f = (const float*)d_in[9];
    const float* W2b = (const float*)d_in[10];
    const float* U2b = (const float*)d_in[11];
    const float* b2b = (const float*)d_in[12];
    const float* W3f = (const float*)d_in[13];
    const float* U3f = (const float*)d_in[14];
    const float* b3f = (const float*)d_in[15];
    const float* W3b = (const float*)d_in[16];
    const float* U3b = (const float*)d_in[17];
    const float* b3b = (const float*)d_in[18];
    const float* Wd1 = (const float*)d_in[19];
    const float* bd1 = (const float*)d_in[20];
    const float* Wd2 = (const float*)d_in[21];
    const float* bd2 = (const float*)d_in[22];

    // workspace: stays within the proven 96MB + 128KB footprint.
    // xz3 (64MB fp16) ALIASES l1out — l1out is dead once L2 has consumed it.
    char* ws = (char*)d_ws;
    void*     l1out = (void*)ws;                                  // [T][B][128] bf16 = 64 MB
    void*     l2out = (void*)(ws + (size_t)64 * 1024 * 1024);     // [T][B][64]  bf16 = 32 MB
    ushort_t* xz3   = (ushort_t*)ws;                              // [T*B][2][4][16] fp16 = 64 MB
    float*    h3    = (float*)(ws + (size_t)96 * 1024 * 1024);    // [B][32] fp32 = 128 KB
    float*    out   = (float*)d_out;

    dim3 grid(BATCH / 16, 2);

    lstm_fused<64, 64, true, true, 0>      // CLASSIC, 4 waves (R3-exact, 170.8us)
        <<<grid, 256, 0, stream>>>(x, W1f, U1f, b1f, W1b, U1b, b1b, l1out);
    lstm_fused<128, 32, false, true, 1>    // SWAP-LDS, 2 waves (R3-exact, ~120us)
        <<<grid, 128, 0, stream>>>(l1out, W2f, U2f, b2f, W2b, U2b, b2b, l2out);
    xz_gemm                                 // xz3 = scale*(l2out@W3 + b3), parallel
        <<<dim3(256), 256, 0, stream>>>((const ushort_t*)l2out, W3f, b3f, W3b, b3b, xz3);
    lstm_rec<16>                            // h-only recurrence, register-resident h
        <<<grid, 64, 0, stream>>>(xz3, U3f, U3b, h3);
    dense_head<<<dim3(BATCH / 256), 256, 0, stream>>>(h3, Wd1, bd1, Wd2, bd2, out);
}

// Round 6
// 496.362 us; speedup vs baseline: 1.2615x; 1.0439x over previous
//
#include <hip/hip_runtime.h>
#include <hip/hip_bf16.h>

#define T_SEQ 256
#define BATCH 1024

typedef __attribute__((ext_vector_type(8))) short  short8;   // 8 bf16 (x32 MFMA frag)
typedef __attribute__((ext_vector_type(4))) float  floatx4;  // MFMA C/D frag
typedef unsigned short ushort_t;
typedef unsigned int   uint_t;

template <int P> struct IC { static constexpr int v = P; };

constexpr float NL2E = -1.4426950408889634f;   // -log2(e): sigmoid = rcp(1+exp2(z))
constexpr float L2E2 =  2.8853900817779268f;   // 2*log2(e): tanh = 1-2*rcp(1+exp2(x))

__device__ __forceinline__ float exp2_fast(float x) {
    float r; asm("v_exp_f32 %0, %1" : "=v"(r) : "v"(x)); return r;
}
__device__ __forceinline__ float rcp_fast(float x) {
    float r; asm("v_rcp_f32 %0, %1" : "=v"(r) : "v"(x)); return r;
}
__device__ __forceinline__ ushort_t f2bf(float f) {
    union { float f; uint_t u; } v; v.f = f;
    uint_t r = v.u + 0x7FFFu + ((v.u >> 16) & 1u);   // RNE
    return (ushort_t)(r >> 16);
}
__device__ __forceinline__ uint_t pk_bf16(float a, float b) {
    union { __hip_bfloat162 h; uint_t u; } v;
    v.h = __float22bfloat162_rn(make_float2(a, b));
    return v.u;
}
// Barrier WITHOUT vmcnt drain: LDS ordering only; global loads/stores stay in flight.
__device__ __forceinline__ void sync_lds() {
    asm volatile("s_waitcnt lgkmcnt(0)\n\ts_barrier" ::: "memory");
}

// ============================= Ledger (measured) ==================================
// L1: CLASSIC 4-wave 167.8-170.8us (R0/R3). SWAP: 200us (R0/R2) -> never.
// L2: SWAP-LDS 2-wave ~120us (R2/R3).  REGH: 231us spills (R1).
// L3: fused swap-1wave 207 (R3) = BEST. REGH 199* / dual 212 (R4) / xz-hoist
//     split 220 (R5) all worse or equal. *199 incl diff attribution noise.
// R4: chain-split acc REGRESSED (+115); dual = +100% work for +3% time.
// R5: xz-hoist null -> per-step floor is BODY-INDEPENDENT (~800ns 1-wave,
//     470-650ns multi-wave). Shared fixed component across ALL variants:
//     40 quarter-rate trans per lane-step (~320cyc trans-unit busy/SIMD).
// R6: group-reciprocal: 1 rcp + 9 mul produces 4 reciprocals -> trans 40->25
//     per step (all 5 rcp groups). Overflow-safe: A=1+exp2(acc), acc<~12 on
//     this data (30-sigma margin to the 2^127 product limit).
// =================================================================================

// 4 sigmoids from 4 prescaled logits with ONE rcp:
// A_r = 1+exp2(z_r); R=rcp(A0A1A2A3); 1/A0 = R*A1*(A2A3), etc.
__device__ __forceinline__ void sig4(const float z[4], float o[4]) {
    const float A0 = 1.0f + exp2_fast(z[0]);
    const float A1 = 1.0f + exp2_fast(z[1]);
    const float A2 = 1.0f + exp2_fast(z[2]);
    const float A3 = 1.0f + exp2_fast(z[3]);
    const float P01 = A0 * A1, P23 = A2 * A3;
    const float R   = rcp_fast(P01 * P23);
    const float R01 = R * P23;      // = 1/(A0*A1)
    const float R23 = R * P01;      // = 1/(A2*A3)
    o[0] = R01 * A1; o[1] = R01 * A0;
    o[2] = R23 * A3; o[3] = R23 * A2;
}
// 4 tanhs (arg prescaled by 2log2e): tanh = 1 - 2*sigmoid'(x)
__device__ __forceinline__ void tanh4(const float z[4], float o[4]) {
    float s[4]; sig4(z, s);
#pragma unroll
    for (int r = 0; r < 4; r++) o[r] = fmaf(-2.0f, s[r], 1.0f);
}

// Fused persistent LSTM layer — R3 structure + grouped-rcp activations.
template <int D, int H, bool IS_FIRST, bool SEQ_OUT, int MODE>
__global__ __launch_bounds__(64 * (H / 16), 1) void lstm_fused(
    const void* __restrict__ xin,
    const float* __restrict__ Wf, const float* __restrict__ Uf, const float* __restrict__ bgf,
    const float* __restrict__ Wb, const float* __restrict__ Ub, const float* __restrict__ bgb,
    void* __restrict__ outp)
{
    constexpr bool SW = (MODE >= 1);             // swapped operand order
    constexpr int UG  = H / 16;                  // waves per block
    constexpr int KSx = D / 32;                  // x k-chunks (16x16x32)
    constexpr int KSh = (H + 31) / 32;           // LDS-h k-chunks
    constexpr int HP  = (H < 32 ? 32 : H) + 8;   // padded h row stride (u16)
    constexpr int G4  = 4 * H;
    constexpr int NTH = 64 * UG;
    static_assert(D % 32 == 0 && T_SEQ % 4 == 0, "shape");

    const int tid  = threadIdx.x;
    const int ug   = tid >> 6;
    const int lane = tid & 63;
    const int lm   = lane & 15;
    const int lq   = lane >> 4;
    const int dir  = blockIdx.y;
    const int b0   = blockIdx.x * 16;

    const float* W  = dir ? Wb  : Wf;
    const float* U  = dir ? Ub  : Uf;
    const float* bg = dir ? bgb : bgf;

    __shared__ __align__(16) ushort_t hbuf[2 * 16 * HP];

    // ---- one-time weight prepack (pre-scaled). Frags identical for both modes. ----
    short8  aw[4][KSx];   // W^T frags
    short8  hw[4][KSh];   // U^T frags
    floatx4 bias4[4];     // persistent bias as MFMA C operand
#pragma unroll
    for (int g = 0; g < 4; g++) {
        const float sc = (g == 2) ? L2E2 : NL2E;
        const int ub = g * H + ug * 16;
        floatx4 b4;
#pragma unroll
        for (int r = 0; r < 4; r++)
            b4[r] = sc * bg[ub + (SW ? lq * 4 + r : lm)];   // classic: bcast over rows
        bias4[g] = b4;
        const int nc = ub + lm;
#pragma unroll
        for (int ks = 0; ks < KSx; ks++) {
            short8 f;
#pragma unroll
            for (int e = 0; e < 8; e++)
                f[e] = (short)f2bf(sc * W[(ks * 32 + lq * 8 + e) * G4 + nc]);
            aw[g][ks] = f;
        }
#pragma unroll
        for (int ks = 0; ks < KSh; ks++) {
            short8 f;
#pragma unroll
            for (int e = 0; e < 8; e++) {
                const int k = ks * 32 + lq * 8 + e;
                f[e] = (k < H) ? (short)f2bf(sc * U[k * G4 + nc]) : (short)0;
            }
            hw[g][ks] = f;
        }
    }

    for (int idx = tid; idx < 2 * 16 * HP; idx += NTH)
        hbuf[idx] = 0;   // h0 = 0; k-padding stays 0 forever

    float cst[4];        // holds 2log2e * c
    float hl[4];
#pragma unroll
    for (int r = 0; r < 4; r++) { cst[r] = 0.f; hl[r] = 0.f; }

    const int t0 = dir ? T_SEQ - 1 : 0;
    // stepping pointers (no per-step 64-bit muls); x loads identical across modes
    const float*    pxf = (const float*)xin + ((size_t)(b0 + lm) * T_SEQ + t0) * D + lq * 8;
    const ushort_t* pxb = (const ushort_t*)xin + ((size_t)t0 * BATCH + b0 + lm) * D + lq * 8;
    const long xstepf = dir ? -(long)D : (long)D;
    const long xstepb = (dir ? -(long)BATCH : (long)BATCH) * D;
    // output pointer, mode-dependent lane->element map
    ushort_t* pout;
    if constexpr (SW)
        pout = (ushort_t*)outp + ((size_t)t0 * BATCH + b0 + lm) * (2 * H) + dir * H +
               ug * 16 + lq * 4;
    else
        pout = (ushort_t*)outp + ((size_t)t0 * BATCH + b0 + lq * 4) * (2 * H) + dir * H +
               ug * 16 + lm;
    const long ostep = (dir ? -(long)BATCH : (long)BATCH) * (2 * H);

    // x prefetch ring, depth 4
    float4 rawf[4][2 * KSx];   // layer-1 path (fp32 input); DCE'd otherwise
    short8 rawb[4][KSx];       // bf16 path

    auto load_slot = [&](auto sl_) {
        constexpr int SL = decltype(sl_)::v;
        if (IS_FIRST) {
#pragma unroll
            for (int ks = 0; ks < KSx; ks++) {
                rawf[SL][2 * ks + 0] = *(const float4*)(pxf + ks * 32 + 0);
                rawf[SL][2 * ks + 1] = *(const float4*)(pxf + ks * 32 + 4);
            }
            pxf += xstepf;
        } else {
#pragma unroll
            for (int ks = 0; ks < KSx; ks++)
                rawb[SL][ks] = *(const short8*)(pxb + ks * 32);
            pxb += xstepb;
        }
    };

    load_slot(IC<0>{}); load_slot(IC<1>{}); load_slot(IC<2>{}); load_slot(IC<3>{});
    __syncthreads();   // hbuf zeros visible

    auto step = [&](auto p_, auto sl_, int s) {
        constexpr int P  = decltype(p_)::v;
        constexpr int SL = decltype(sl_)::v;

        // h frags from LDS (issued first; x-MFMAs overlap the lgkm latency)
        short8 fh[KSh];
#pragma unroll
        for (int ks = 0; ks < KSh; ks++)
            fh[ks] = *(const short8*)&hbuf[(P * 16 + lm) * HP + ks * 32 + lq * 8];

        // x frags from the register ring (packed fp32->bf16 conv on layer 1)
        short8 av[KSx];
        if (IS_FIRST) {
#pragma unroll
            for (int ks = 0; ks < KSx; ks++) {
                union { short8 s; uint_t u[4]; } f;
                const float* ra = (const float*)&rawf[SL][2 * ks];
#pragma unroll
                for (int e = 0; e < 4; e++) f.u[e] = pk_bf16(ra[2 * e], ra[2 * e + 1]);
                av[ks] = f.s;
            }
        } else {
#pragma unroll
            for (int ks = 0; ks < KSx; ks++) av[ks] = rawb[SL][ks];
        }

        floatx4 acc[4];
        // first x-MFMA carries the (persistent) bias as C — no per-step init movs
#pragma unroll
        for (int g = 0; g < 4; g++)
            acc[g] = SW
                ? __builtin_amdgcn_mfma_f32_16x16x32_bf16(aw[g][0], av[0], bias4[g], 0, 0, 0)
                : __builtin_amdgcn_mfma_f32_16x16x32_bf16(av[0], aw[g][0], bias4[g], 0, 0, 0);
#pragma unroll
        for (int ks = 1; ks < KSx; ks++)
#pragma unroll
            for (int g = 0; g < 4; g++)
                acc[g] = SW
                    ? __builtin_amdgcn_mfma_f32_16x16x32_bf16(aw[g][ks], av[ks], acc[g], 0, 0, 0)
                    : __builtin_amdgcn_mfma_f32_16x16x32_bf16(av[ks], aw[g][ks], acc[g], 0, 0, 0);

        if (s + 4 < T_SEQ) load_slot(sl_);   // refill consumed slot (uniform branch)

        // recurrent part last (shortest possible h -> MFMA distance)
#pragma unroll
        for (int ks = 0; ks < KSh; ks++)
#pragma unroll
            for (int g = 0; g < 4; g++)
                acc[g] = SW
                    ? __builtin_amdgcn_mfma_f32_16x16x32_bf16(hw[g][ks], fh[ks], acc[g], 0, 0, 0)
                    : __builtin_amdgcn_mfma_f32_16x16x32_bf16(fh[ks], hw[g][ks], acc[g], 0, 0, 0);

        // gates + c/h update — grouped-rcp activations (trans 40 -> 25 per step)
        float zi[4], zf[4], zg[4], zo[4];
#pragma unroll
        for (int r = 0; r < 4; r++) {
            zi[r] = acc[0][r]; zf[r] = acc[1][r];
            zg[r] = acc[2][r]; zo[r] = acc[3][r];
        }
        float gi[4], gf[4], gg[4], go[4];
        sig4(zi, gi); sig4(zf, gf); tanh4(zg, gg); sig4(zo, go);
        float cz[4];
#pragma unroll
        for (int r = 0; r < 4; r++) {
            cst[r] = fmaf(gf[r], cst[r], L2E2 * (gi[r] * gg[r]));
            cz[r] = cst[r];
        }
        float tc[4];
        tanh4(cz, tc);
        float hv[4];
#pragma unroll
        for (int r = 0; r < 4; r++) hv[r] = go[r] * tc[r];

        if constexpr (SW) {
            const uint_t d0 = pk_bf16(hv[0], hv[1]);   // units +0,+1
            const uint_t d1 = pk_bf16(hv[2], hv[3]);   // units +2,+3
            uint2 wv; wv.x = d0; wv.y = d1;
            *(uint2*)&hbuf[((P ^ 1) * 16 + lm) * HP + ug * 16 + lq * 4] = wv;   // 1x b64
            if (SEQ_OUT) {
                uint2 ov; ov.x = d0; ov.y = d1;
                *(uint2*)&pout[0] = ov;                 // 1x dwordx2
            } else {
#pragma unroll
                for (int r = 0; r < 4; r++) hl[r] = hv[r];
            }
        } else {
            // classic: lane holds 4 ROWS (lq*4+r) of one unit column (ug*16+lm)
#pragma unroll
            for (int r = 0; r < 4; r++) {
                const ushort_t hw_ = f2bf(hv[r]);
                hbuf[((P ^ 1) * 16 + lq * 4 + r) * HP + ug * 16 + lm] = hw_;
                if (SEQ_OUT) pout[r * 2 * H] = hw_;
                else         hl[r] = hv[r];
            }
        }
        pout += ostep;
        if (UG > 1) sync_lds();   // lgkm-only; single-wave layers need no barrier
    };

    for (int s = 0; s < T_SEQ; s += 4) {
        step(IC<0>{}, IC<0>{}, s);
        step(IC<1>{}, IC<1>{}, s + 1);
        step(IC<0>{}, IC<2>{}, s + 2);
        step(IC<1>{}, IC<3>{}, s + 3);
    }

    if (!SEQ_OUT) {
        float* op = (float*)outp;
        if constexpr (SW) {
            float4 v4 = make_float4(hl[0], hl[1], hl[2], hl[3]);
            *(float4*)&op[(size_t)(b0 + lm) * (2 * H) + dir * H + ug * 16 + lq * 4] = v4;
        } else {
#pragma unroll
            for (int r = 0; r < 4; r++)
                op[(size_t)(b0 + lq * 4 + r) * (2 * H) + dir * H + ug * 16 + lm] = hl[r];
        }
    }
}

// Dense head: relu6(x@Wd1+bd1) @ Wd2 + bd2 -> softmax(2). One row per thread.
__global__ __launch_bounds__(256) void dense_head(
    const float* __restrict__ h3, const float* __restrict__ Wd1, const float* __restrict__ bd1,
    const float* __restrict__ Wd2, const float* __restrict__ bd2, float* __restrict__ out)
{
    const int b = blockIdx.x * blockDim.x + threadIdx.x;
    if (b >= BATCH) return;
    float x[32];
#pragma unroll
    for (int k = 0; k < 32; k++) x[k] = h3[b * 32 + k];
    float y[16];
#pragma unroll
    for (int jj = 0; jj < 16; jj++) {
        float a = bd1[jj];
#pragma unroll
        for (int k = 0; k < 32; k++) a = fmaf(x[k], Wd1[k * 16 + jj], a);
        y[jj] = fminf(fmaxf(a, 0.0f), 6.0f);
    }
    float l0 = bd2[0], l1 = bd2[1];
#pragma unroll
    for (int k = 0; k < 16; k++) {
        l0 = fmaf(y[k], Wd2[k * 2 + 0], l0);
        l1 = fmaf(y[k], Wd2[k * 2 + 1], l1);
    }
    const float m = fmaxf(l0, l1);
    const float e0 = __expf(l0 - m), e1 = __expf(l1 - m);
    const float inv = 1.0f / (e0 + e1);
    out[b * 2 + 0] = e0 * inv;
    out[b * 2 + 1] = e1 * inv;
}

extern "C" void kernel_launch(void* const* d_in, const int* in_sizes, int n_in,
                              void* d_out, int out_size, void* d_ws, size_t ws_size,
                              hipStream_t stream)
{
    const float* x   = (const float*)d_in[0];
    const float* W1f = (const float*)d_in[1];
    const float* U1f = (const float*)d_in[2];
    const float* b1f = (const float*)d_in[3];
    const float* W1b = (const float*)d_in[4];
    const float* U1b = (const float*)d_in[5];
    const float* b1b = (const float*)d_in[6];
    const float* W2f = (const float*)d_in[7];
    const float* U2f = (const float*)d_in[8];
    const float* b2f = (const float*)d_in[9];
    const float* W2b = (const float*)d_in[10];
    const float* U2b = (const float*)d_in[11];
    const float* b2b = (const float*)d_in[12];
    const float* W3f = (const float*)d_in[13];
    const float* U3f = (const float*)d_in[14];
    const float* b3f = (const float*)d_in[15];
    const float* W3b = (const float*)d_in[16];
    const float* U3b = (const float*)d_in[17];
    const float* b3b = (const float*)d_in[18];
    const float* Wd1 = (const float*)d_in[19];
    const float* bd1 = (const float*)d_in[20];
    const float* Wd2 = (const float*)d_in[21];
    const float* bd2 = (const float*)d_in[22];

    // workspace: the proven 96 MB + 128 KB footprint
    char* ws = (char*)d_ws;
    void*  l1out = (void*)ws;                                  // [T][B][128] bf16 = 64 MB
    void*  l2out = (void*)(ws + (size_t)64 * 1024 * 1024);     // [T][B][64]  bf16 = 32 MB
    float* h3    = (float*)(ws + (size_t)96 * 1024 * 1024);    // [B][32] fp32 = 128 KB
    float* out   = (float*)d_out;

    dim3 grid(BATCH / 16, 2);

    lstm_fused<64, 64, true, true, 0>      // CLASSIC, 4 waves (best measured for L1)
        <<<grid, 256, 0, stream>>>(x, W1f, U1f, b1f, W1b, U1b, b1b, l1out);
    lstm_fused<128, 32, false, true, 1>    // SWAP-LDS, 2 waves (best measured for L2)
        <<<grid, 128, 0, stream>>>(l1out, W2f, U2f, b2f, W2b, U2b, b2b, l2out);
    lstm_fused<64, 16, false, false, 1>    // SWAP-LDS, 1 wave, barrier-free (best L3)
        <<<grid, 64, 0, stream>>>(l2out, W3f, U3f, b3f, W3b, U3b, b3b, h3);
    dense_head<<<dim3(BATCH / 256), 256, 0, stream>>>(h3, Wd1, bd1, Wd2, bd2, out);
}